// Round 7
// baseline (626.320 us; speedup 1.0000x reference)
//
#include <hip/hip_runtime.h>
#include <hip/hip_cooperative_groups.h>
#include <math.h>

namespace cg = cooperative_groups;

// ---------------- problem constants ----------------
#define BATCH   16
#define T_LEN   262144
#define NB      16          // biquad stages
#define L       64          // samples per chunk
#define GRP     64          // chunks per group (== wave width)
#define SUB     16          // chunks per sub-group
#define CHAINS  4           // sub-groups per wave
#define NSUB    256         // sub-groups per batch
#define NSUP    16          // super-groups per batch
#define NG      64          // groups (waves/blocks) per batch
#define NCHUNK  4096        // chunks per batch

#define DPI 3.14159265358979323846264338327950288

// ---------------- ws layout (floats) ----------------
#define OFF_COEF  0          // [16][96]
#define OFF_A64   1536       // [16][32][32]  A^64    (f32, f64-computed)
#define OFF_A1K   17920      // [16][32][32]  A^1024
#define OFF_A16K  34304      // [16][32][32]  A^16384
#define OFF_QEND  50688      // [16][256][32] zero-init sub-group totals
#define OFF_QSUP  181760     // [16][16][32]  zero-init super totals
#define OFF_SSUP  189952     // [16][16][32]  super start states
#define OFF_SARR  198144     // [16][256][32] sub-group start states
// total = 329216 floats ~= 1.3 MB

// ---------------- stage coefficient math (f64) ----------------
__device__ inline void stage_coefs(int i, double fn, double gn, double qn,
                                   double& B0, double& B1, double& B2,
                                   double& A1, double& A2) {
    const double FS = 96000.0;
    double Q    = exp(log(0.5) + qn * (log(16.0) - log(0.5)));
    double gain = -24.0 + gn * 48.0;
    double lo, hi;
    if (i == 0)            { lo = 20.0;   hi = 500.0;   }
    else if (i == 15)      { lo = 5000.0; hi = 20000.0; }
    else if (i == 1 || i == 14) { lo = 50.0; hi = 16000.0; }
    else                   { lo = 100.0;  hi = 15000.0; }
    double fc    = exp(log(lo) + fn * (log(hi) - log(lo)));
    double w0    = 2.0 * DPI * fc / FS;
    double alpha = sin(w0) / (2.0 * Q);
    double c     = cos(w0);
    double b0, b1, b2, a0, a1, a2;
    if (i == 0) {
        b0 = (1.0 + c) * 0.5; b1 = -(1.0 + c); b2 = (1.0 + c) * 0.5;
        a0 = 1.0 + alpha; a1 = -2.0 * c; a2 = 1.0 - alpha;
    } else if (i == 15) {
        b0 = (1.0 - c) * 0.5; b1 = 1.0 - c; b2 = (1.0 - c) * 0.5;
        a0 = 1.0 + alpha; a1 = -2.0 * c; a2 = 1.0 - alpha;
    } else if (i == 1) {
        double A = pow(10.0, gain / 40.0), sA = sqrt(A);
        b0 = A * ((A + 1.0) - (A - 1.0) * c + 2.0 * sA * alpha);
        b1 = 2.0 * A * ((A - 1.0) - (A + 1.0) * c);
        b2 = A * ((A + 1.0) - (A - 1.0) * c - 2.0 * sA * alpha);
        a0 = (A + 1.0) + (A - 1.0) * c + 2.0 * sA * alpha;
        a1 = -2.0 * ((A - 1.0) + (A + 1.0) * c);
        a2 = (A + 1.0) + (A - 1.0) * c - 2.0 * sA * alpha;
    } else if (i == 14) {
        double A = pow(10.0, gain / 40.0), sA = sqrt(A);
        b0 = A * ((A + 1.0) + (A - 1.0) * c + 2.0 * sA * alpha);
        b1 = -2.0 * A * ((A - 1.0) + (A + 1.0) * c);
        b2 = A * ((A + 1.0) + (A - 1.0) * c - 2.0 * sA * alpha);
        a0 = (A + 1.0) - (A - 1.0) * c + 2.0 * sA * alpha;
        a1 = 2.0 * ((A - 1.0) - (A + 1.0) * c);
        a2 = (A + 1.0) - (A - 1.0) * c - 2.0 * sA * alpha;
    } else {
        double A = pow(10.0, gain / 40.0);
        b0 = 1.0 + alpha * A; b1 = -2.0 * c; b2 = 1.0 - alpha * A;
        a0 = 1.0 + alpha / A; a1 = -2.0 * c; a2 = 1.0 - alpha / A;
    }
    B0 = b0 / a0; B1 = b1 / a0; B2 = b2 / a0; A1 = a1 / a0; A2 = a2 / a0;
}

// ---------------- K0: coefs + A^64 / A^1024 / A^16384 per batch (f64) -------
// f64 is REQUIRED for the high-power chain: the cascade matrix is non-normal
// and its intermediate powers (A^2048..A^8192) transiently exceed f32 range
// even though the saved matrices are f32-representable (round-6 f32 chain
// produced Inf -> fmaf(Inf,0)=NaN). Squaring mapping: thread t owns column
// c=t&31, rows r0+{0,8,16,24}; column read = 32 consecutive doubles (2-way
// bank alias = free), row reads broadcast.
__global__ __launch_bounds__(256) void k0_setup(const float* __restrict__ params,
                                                float* __restrict__ coefs,
                                                float* __restrict__ A64,
                                                float* __restrict__ A1K,
                                                float* __restrict__ A16K) {
    int b = blockIdx.x;
    int t = threadIdx.x;
    __shared__ double cf[NB][5];
    __shared__ double M1[32 * 32];
    __shared__ double M2[32 * 32];

    if (t < NB) {
        double B0, B1, B2, A1, A2;
        stage_coefs(t, (double)params[b * 50 + t * 3 + 0],
                       (double)params[b * 50 + t * 3 + 1],
                       (double)params[b * 50 + t * 3 + 2], B0, B1, B2, A1, A2);
        float f0 = (float)B0, f1 = (float)B1, f2 = (float)B2, f3 = (float)A1, f4 = (float)A2;
        cf[t][0] = (double)f0; cf[t][1] = (double)f1; cf[t][2] = (double)f2;
        cf[t][3] = (double)f3; cf[t][4] = (double)f4;
        float* cp = coefs + b * 96 + t * 5;
        cp[0] = f0; cp[1] = f1; cp[2] = f2; cp[3] = f3; cp[4] = f4;
    }
    if (t == NB) {
        double indb = -60.0 + (double)params[b * 50 + 48] * 60.0;
        coefs[b * 96 + 80] = (float)pow(10.0, indb / 20.0);
    }
    if (t == NB + 1) {
        double outdb = -60.0 + (double)params[b * 50 + 49] * 60.0;
        coefs[b * 96 + 81] = (float)pow(10.0, outdb / 20.0);
    }
    __syncthreads();

    // build A: column t = one cascade step (u=0) applied to unit state e_t
    if (t < 32) {
        double s1[NB], s2[NB];
#pragma unroll
        for (int i = 0; i < NB; i++) {
            s1[i] = (t == 2 * i) ? 1.0 : 0.0;
            s2[i] = (t == 2 * i + 1) ? 1.0 : 0.0;
        }
        double u = 0.0;
#pragma unroll
        for (int i = 0; i < NB; i++) {
            double y  = cf[i][0] * u + s1[i];
            double n1 = cf[i][1] * u - cf[i][3] * y + s2[i];
            double n2 = cf[i][2] * u - cf[i][4] * y;
            s1[i] = n1; s2[i] = n2; u = y;
        }
#pragma unroll
        for (int i = 0; i < NB; i++) {
            M1[(2 * i) * 32 + t]     = s1[i];
            M1[(2 * i + 1) * 32 + t] = s2[i];
        }
    }
    __syncthreads();

    // 14 squarings; after iter sq: A^(2^(sq+1)).
    // Save A^64 (sq=5), A^1024 (sq=9), A^16384 (sq=13).
    int c  = t & 31;
    int r0 = t >> 5;
    double* src = M1;
    double* dst = M2;
    for (int sq = 0; sq < 14; sq++) {
        double acc[4] = {0.0, 0.0, 0.0, 0.0};
        for (int k = 0; k < 32; k++) {
            double bv = src[k * 32 + c];
#pragma unroll
            for (int e = 0; e < 4; e++)
                acc[e] += src[(e * 8 + r0) * 32 + k] * bv;
        }
#pragma unroll
        for (int e = 0; e < 4; e++) dst[(e * 8 + r0) * 32 + c] = acc[e];
        __syncthreads();
        { double* tmp = src; src = dst; dst = tmp; }
        float* out_m = (sq == 5) ? A64 : (sq == 9) ? A1K : (sq == 13) ? A16K : nullptr;
        if (out_m) {
#pragma unroll
            for (int e = 0; e < 4; e++) {
                int idx = (e * 8 + r0) * 32 + c;
                out_m[b * 1024 + idx] = (float)src[idx];
            }
        }
        __syncthreads();
    }
}

// single half-split matvec step: q' = A q + add (add pre-masked to half 0)
__device__ __forceinline__ float mv_step(const float* ar, float q, float addv, int half) {
    float acc = addv;
#pragma unroll
    for (int t = 0; t < 16; t++)
        acc = fmaf(ar[t], __shfl(q, half * 16 + t, 64), acc);
    acc += __shfl_xor(acc, 32, 64);
    return acc;
}

// ---------------- mega: cascade + hierarchical combine + output -------------
// 1024 single-wave blocks (4/CU, all co-resident). plds persists across
// phases: the P matrix never touches HBM. grid.sync replaces launch gaps.
__global__ __launch_bounds__(64, 1) void mega(const float* __restrict__ audio,
                                              const float* __restrict__ coefs,
                                              const float* __restrict__ A64,
                                              const float* __restrict__ A1K,
                                              const float* __restrict__ A16K,
                                              float* __restrict__ Qend,
                                              float* __restrict__ Qsup,
                                              float* __restrict__ Ssup,
                                              float* __restrict__ Sarr,
                                              float* __restrict__ out) {
    cg::grid_group grid = cg::this_grid();
    int blk   = blockIdx.x;
    int batch = blk >> 6;
    int grp   = blk & 63;
    int lane  = threadIdx.x;
    int chunk = grp * GRP + lane;
    int row   = lane & 31;
    int half  = lane >> 5;

    __shared__ float plds[GRP][33];

    const float* cf = coefs + batch * 96;
    float c0[NB], c1[NB], c2[NB], c3[NB], c4[NB];
#pragma unroll
    for (int i = 0; i < NB; i++) {
        c0[i] = cf[i * 5 + 0]; c1[i] = cf[i * 5 + 1]; c2[i] = cf[i * 5 + 2];
        c3[i] = cf[i * 5 + 3]; c4[i] = cf[i * 5 + 4];
    }
    float ing  = cf[80];
    float outg = cf[81];

    float ar64[16];
    {
        const float* ap = A64 + batch * 1024 + row * 32 + half * 16;
#pragma unroll
        for (int j = 0; j < 16; j++) ar64[j] = ap[j];
    }

    // ---------- Phase B: zero-init cascade + 4 chains -> Qend ---------------
    {
        float s1[NB], s2[NB];
#pragma unroll
        for (int i = 0; i < NB; i++) { s1[i] = 0.f; s2[i] = 0.f; }
        const float4* xp = (const float4*)(audio + (size_t)batch * T_LEN + (size_t)chunk * L);
        float4 a0v = xp[0];
        float4 a1v = xp[1];
#pragma unroll 1
        for (int tt = 0; tt < 16; tt++) {
            float4 fut = xp[(tt < 14) ? (tt + 2) : 15];
            float xs[4] = {a0v.x, a0v.y, a0v.z, a0v.w};
#pragma unroll
            for (int j = 0; j < 4; j++) {
                float u = ing * xs[j];
#pragma unroll
                for (int i = 0; i < NB; i++) {
                    float y  = fmaf(c0[i], u, s1[i]);
                    float n1 = fmaf(c1[i], u, s2[i]); n1 = fmaf(-c3[i], y, n1);
                    float n2 = c2[i] * u;             n2 = fmaf(-c4[i], y, n2);
                    s1[i] = n1; s2[i] = n2; u = y;
                }
            }
            a0v = a1v; a1v = fut;
        }
#pragma unroll
        for (int i = 0; i < NB; i++) {
            plds[lane][2 * i]     = s1[i];
            plds[lane][2 * i + 1] = s2[i];
        }
    }
    __syncthreads();
    {
        float q0 = 0.f, q1 = 0.f, q2 = 0.f, q3 = 0.f;
#pragma unroll 1
        for (int j = 0; j < SUB; j++) {
            float a0 = (half == 0) ? plds[0 * SUB + j][row] : 0.f;
            float a1 = (half == 0) ? plds[1 * SUB + j][row] : 0.f;
            float a2 = (half == 0) ? plds[2 * SUB + j][row] : 0.f;
            float a3 = (half == 0) ? plds[3 * SUB + j][row] : 0.f;
#pragma unroll
            for (int t = 0; t < 16; t++) {
                float w = ar64[t];
                int src = half * 16 + t;
                a0 = fmaf(w, __shfl(q0, src, 64), a0);
                a1 = fmaf(w, __shfl(q1, src, 64), a1);
                a2 = fmaf(w, __shfl(q2, src, 64), a2);
                a3 = fmaf(w, __shfl(q3, src, 64), a3);
            }
            a0 += __shfl_xor(a0, 32, 64);
            a1 += __shfl_xor(a1, 32, 64);
            a2 += __shfl_xor(a2, 32, 64);
            a3 += __shfl_xor(a3, 32, 64);
            q0 = a0; q1 = a1; q2 = a2; q3 = a3;
        }
        if (lane < 32) {
            float* qe = Qend + ((size_t)(batch * NSUB + grp * CHAINS)) * 32 + row;
            qe[0] = q0; qe[32] = q1; qe[64] = q2; qe[96] = q3;
        }
    }

    __threadfence();
    grid.sync();   // S1: Qend visible

    // ---------- Phase C1: sub totals -> super totals (16 blocks/batch) ------
    float ar1k[16];
    if (grp < 16) {
        int sup = grp;
        const float* ap = A1K + batch * 1024 + row * 32 + half * 16;
#pragma unroll
        for (int j = 0; j < 16; j++) ar1k[j] = ap[j];
        float pv[16];
#pragma unroll
        for (int j = 0; j < 16; j++)
            pv[j] = (half == 0) ? Qend[((size_t)(batch * NSUB + sup * 16 + j)) * 32 + row] : 0.f;
        float q = 0.f;
#pragma unroll 1
        for (int j = 0; j < 16; j++) q = mv_step(ar1k, q, pv[j], half);
        if (lane < 32) Qsup[((size_t)(batch * NSUP + sup)) * 32 + row] = q;
    }

    __threadfence();
    grid.sync();   // S2: Qsup visible

    // ---------- Phase C2: super scan (1 block/batch) ------------------------
    if (grp == 0) {
        float ark[16];
        const float* ap = A16K + batch * 1024 + row * 32 + half * 16;
#pragma unroll
        for (int j = 0; j < 16; j++) ark[j] = ap[j];
        float pv[16];
#pragma unroll
        for (int j = 0; j < 16; j++)
            pv[j] = (half == 0) ? Qsup[((size_t)(batch * NSUP + j)) * 32 + row] : 0.f;
        float S = 0.f;
#pragma unroll 1
        for (int s = 0; s < 16; s++) {
            if (lane < 32) Ssup[((size_t)(batch * NSUP + s)) * 32 + row] = S;
            S = mv_step(ark, S, pv[s], half);
        }
    }

    __threadfence();
    grid.sync();   // S3: Ssup visible

    // ---------- Phase C3: seeded sub scan -> Sarr ---------------------------
    if (grp < 16) {
        int sup = grp;
        float pv[16];
#pragma unroll
        for (int j = 0; j < 16; j++)
            pv[j] = (half == 0) ? Qend[((size_t)(batch * NSUB + sup * 16 + j)) * 32 + row] : 0.f;
        float q = Ssup[((size_t)(batch * NSUP + sup)) * 32 + row];   // replicated
#pragma unroll 1
        for (int j = 0; j < 16; j++) {
            if (lane < 32) Sarr[((size_t)(batch * NSUB + sup * 16 + j)) * 32 + row] = q;
            q = mv_step(ar1k, q, pv[j], half);
        }
    }

    __threadfence();
    grid.sync();   // S4: Sarr visible

    // ---------- Phase D: seeded chains + corrected cascade -> out -----------
    {
        const float* sp = Sarr + ((size_t)(batch * NSUB + grp * CHAINS)) * 32 + row;
        float q0 = sp[0], q1 = sp[32], q2 = sp[64], q3 = sp[96];
#pragma unroll 1
        for (int j = 0; j < SUB; j++) {
            float a0 = (half == 0) ? plds[0 * SUB + j][row] : 0.f;
            float a1 = (half == 0) ? plds[1 * SUB + j][row] : 0.f;
            float a2 = (half == 0) ? plds[2 * SUB + j][row] : 0.f;
            float a3 = (half == 0) ? plds[3 * SUB + j][row] : 0.f;
            if (half == 0) {
                plds[0 * SUB + j][row] = q0;
                plds[1 * SUB + j][row] = q1;
                plds[2 * SUB + j][row] = q2;
                plds[3 * SUB + j][row] = q3;
            }
#pragma unroll
            for (int t = 0; t < 16; t++) {
                float w = ar64[t];
                int src = half * 16 + t;
                a0 = fmaf(w, __shfl(q0, src, 64), a0);
                a1 = fmaf(w, __shfl(q1, src, 64), a1);
                a2 = fmaf(w, __shfl(q2, src, 64), a2);
                a3 = fmaf(w, __shfl(q3, src, 64), a3);
            }
            a0 += __shfl_xor(a0, 32, 64);
            a1 += __shfl_xor(a1, 32, 64);
            a2 += __shfl_xor(a2, 32, 64);
            a3 += __shfl_xor(a3, 32, 64);
            q0 = a0; q1 = a1; q2 = a2; q3 = a3;
        }
    }
    __syncthreads();

    {
        float s1[NB], s2[NB];
#pragma unroll
        for (int i = 0; i < NB; i++) {
            s1[i] = plds[lane][2 * i];
            s2[i] = plds[lane][2 * i + 1];
        }
        const float4* xp = (const float4*)(audio + (size_t)batch * T_LEN + (size_t)chunk * L);
        float4* yp = (float4*)(out + (size_t)batch * T_LEN + (size_t)chunk * L);
        float4 a0v = xp[0];
        float4 a1v = xp[1];
#pragma unroll 1
        for (int tt = 0; tt < 16; tt++) {
            float4 fut = xp[(tt < 14) ? (tt + 2) : 15];
            float xs[4] = {a0v.x, a0v.y, a0v.z, a0v.w};
            float ys[4];
#pragma unroll
            for (int j = 0; j < 4; j++) {
                float u = ing * xs[j];
#pragma unroll
                for (int i = 0; i < NB; i++) {
                    float y  = fmaf(c0[i], u, s1[i]);
                    float n1 = fmaf(c1[i], u, s2[i]); n1 = fmaf(-c3[i], y, n1);
                    float n2 = c2[i] * u;             n2 = fmaf(-c4[i], y, n2);
                    s1[i] = n1; s2[i] = n2; u = y;
                }
                ys[j] = outg * u;
            }
            float4 yv; yv.x = ys[0]; yv.y = ys[1]; yv.z = ys[2]; yv.w = ys[3];
            yp[tt] = yv;
            a0v = a1v; a1v = fut;
        }
    }
}

// ---------------- launcher ----------------
extern "C" void kernel_launch(void* const* d_in, const int* in_sizes, int n_in,
                              void* d_out, int out_size, void* d_ws, size_t ws_size,
                              hipStream_t stream) {
    const float* audio  = (const float*)d_in[0];
    const float* params = (const float*)d_in[1];
    float* out = (float*)d_out;
    float* ws  = (float*)d_ws;

    float* coefs = ws + OFF_COEF;
    float* A64   = ws + OFF_A64;
    float* A1K   = ws + OFF_A1K;
    float* A16K  = ws + OFF_A16K;
    float* Qend  = ws + OFF_QEND;
    float* Qsup  = ws + OFF_QSUP;
    float* Ssup  = ws + OFF_SSUP;
    float* Sarr  = ws + OFF_SARR;

    k0_setup<<<BATCH, 256, 0, stream>>>(params, coefs, A64, A1K, A16K);

    const float* c_coefs = coefs;
    const float* c_A64   = A64;
    const float* c_A1K   = A1K;
    const float* c_A16K  = A16K;
    void* args[] = {(void*)&audio, (void*)&c_coefs, (void*)&c_A64, (void*)&c_A1K,
                    (void*)&c_A16K, (void*)&Qend, (void*)&Qsup, (void*)&Ssup,
                    (void*)&Sarr, (void*)&out};
    hipLaunchCooperativeKernel((const void*)mega, dim3(BATCH * NG), dim3(64),
                               args, 0, stream);
}

// Round 8
// 173.032 us; speedup vs baseline: 3.6197x; 3.6197x over previous
//
#include <hip/hip_runtime.h>
#include <math.h>

// ---------------- problem constants ----------------
#define BATCH   16
#define T_LEN   262144
#define NB      16          // biquad stages
#define L       64          // samples per chunk
#define GRP     64          // chunks per group (== wave width)
#define SUB     16          // chunks per sub-group
#define CHAINS  4           // sub-groups per wave
#define NSUB    256         // sub-groups per batch
#define NSUP    16          // super-groups per batch
#define NG      64          // groups (waves) per batch
#define NCHUNK  4096        // chunks per batch

#define DPI 3.14159265358979323846264338327950288

// ---------------- ws layout (floats) ----------------
#define OFF_COEF  0          // [16][96]
#define OFF_A64   1536       // [16][32][32]  A^64    (f32, f64-computed)
#define OFF_A1K   17920      // [16][32][32]  A^1024
#define OFF_A16K  34304      // [16][32][32]  A^16384
#define OFF_QEND  50688      // [16][256][32] zero-init sub-group totals
#define OFF_SARR  181760     // [16][256][32] sub-group start states
#define OFF_P     312832     // [16][64][32][64] chunk-final states, TRANSPOSED:
                             //   P[batch][grp][state][chunk-in-grp] -> lane-
                             //   consecutive = chunk -> fully coalesced
// total = 312832 + 16*64*2048 = 3,409,984 floats ~= 13.6 MB

// ---------------- stage coefficient math (f64) ----------------
__device__ inline void stage_coefs(int i, double fn, double gn, double qn,
                                   double& B0, double& B1, double& B2,
                                   double& A1, double& A2) {
    const double FS = 96000.0;
    double Q    = exp(log(0.5) + qn * (log(16.0) - log(0.5)));
    double gain = -24.0 + gn * 48.0;
    double lo, hi;
    if (i == 0)            { lo = 20.0;   hi = 500.0;   }
    else if (i == 15)      { lo = 5000.0; hi = 20000.0; }
    else if (i == 1 || i == 14) { lo = 50.0; hi = 16000.0; }
    else                   { lo = 100.0;  hi = 15000.0; }
    double fc    = exp(log(lo) + fn * (log(hi) - log(lo)));
    double w0    = 2.0 * DPI * fc / FS;
    double alpha = sin(w0) / (2.0 * Q);
    double c     = cos(w0);
    double b0, b1, b2, a0, a1, a2;
    if (i == 0) {
        b0 = (1.0 + c) * 0.5; b1 = -(1.0 + c); b2 = (1.0 + c) * 0.5;
        a0 = 1.0 + alpha; a1 = -2.0 * c; a2 = 1.0 - alpha;
    } else if (i == 15) {
        b0 = (1.0 - c) * 0.5; b1 = 1.0 - c; b2 = (1.0 - c) * 0.5;
        a0 = 1.0 + alpha; a1 = -2.0 * c; a2 = 1.0 - alpha;
    } else if (i == 1) {
        double A = pow(10.0, gain / 40.0), sA = sqrt(A);
        b0 = A * ((A + 1.0) - (A - 1.0) * c + 2.0 * sA * alpha);
        b1 = 2.0 * A * ((A - 1.0) - (A + 1.0) * c);
        b2 = A * ((A + 1.0) - (A - 1.0) * c - 2.0 * sA * alpha);
        a0 = (A + 1.0) + (A - 1.0) * c + 2.0 * sA * alpha;
        a1 = -2.0 * ((A - 1.0) + (A + 1.0) * c);
        a2 = (A + 1.0) + (A - 1.0) * c - 2.0 * sA * alpha;
    } else if (i == 14) {
        double A = pow(10.0, gain / 40.0), sA = sqrt(A);
        b0 = A * ((A + 1.0) + (A - 1.0) * c + 2.0 * sA * alpha);
        b1 = -2.0 * A * ((A - 1.0) + (A + 1.0) * c);
        b2 = A * ((A + 1.0) + (A - 1.0) * c - 2.0 * sA * alpha);
        a0 = (A + 1.0) - (A - 1.0) * c + 2.0 * sA * alpha;
        a1 = 2.0 * ((A - 1.0) - (A + 1.0) * c);
        a2 = (A + 1.0) - (A - 1.0) * c - 2.0 * sA * alpha;
    } else {
        double A = pow(10.0, gain / 40.0);
        b0 = 1.0 + alpha * A; b1 = -2.0 * c; b2 = 1.0 - alpha * A;
        a0 = 1.0 + alpha / A; a1 = -2.0 * c; a2 = 1.0 - alpha / A;
    }
    B0 = b0 / a0; B1 = b1 / a0; B2 = b2 / a0; A1 = a1 / a0; A2 = a2 / a0;
}

// ---------------- K0: coefs + A^64 / A^1024 / A^16384 (f64) -----------------
// f64 REQUIRED for the high-power chain (round-6 f32 chain overflowed to
// Inf/NaN on intermediate powers of the non-normal cascade matrix).
__global__ __launch_bounds__(256) void k0_setup(const float* __restrict__ params,
                                                float* __restrict__ coefs,
                                                float* __restrict__ A64,
                                                float* __restrict__ A1K,
                                                float* __restrict__ A16K) {
    int b = blockIdx.x;
    int t = threadIdx.x;
    __shared__ double cf[NB][5];
    __shared__ double M1[32 * 32];
    __shared__ double M2[32 * 32];

    if (t < NB) {
        double B0, B1, B2, A1, A2;
        stage_coefs(t, (double)params[b * 50 + t * 3 + 0],
                       (double)params[b * 50 + t * 3 + 1],
                       (double)params[b * 50 + t * 3 + 2], B0, B1, B2, A1, A2);
        float f0 = (float)B0, f1 = (float)B1, f2 = (float)B2, f3 = (float)A1, f4 = (float)A2;
        cf[t][0] = (double)f0; cf[t][1] = (double)f1; cf[t][2] = (double)f2;
        cf[t][3] = (double)f3; cf[t][4] = (double)f4;
        float* cp = coefs + b * 96 + t * 5;
        cp[0] = f0; cp[1] = f1; cp[2] = f2; cp[3] = f3; cp[4] = f4;
    }
    if (t == NB) {
        double indb = -60.0 + (double)params[b * 50 + 48] * 60.0;
        coefs[b * 96 + 80] = (float)pow(10.0, indb / 20.0);
    }
    if (t == NB + 1) {
        double outdb = -60.0 + (double)params[b * 50 + 49] * 60.0;
        coefs[b * 96 + 81] = (float)pow(10.0, outdb / 20.0);
    }
    __syncthreads();

    if (t < 32) {
        double s1[NB], s2[NB];
#pragma unroll
        for (int i = 0; i < NB; i++) {
            s1[i] = (t == 2 * i) ? 1.0 : 0.0;
            s2[i] = (t == 2 * i + 1) ? 1.0 : 0.0;
        }
        double u = 0.0;
#pragma unroll
        for (int i = 0; i < NB; i++) {
            double y  = cf[i][0] * u + s1[i];
            double n1 = cf[i][1] * u - cf[i][3] * y + s2[i];
            double n2 = cf[i][2] * u - cf[i][4] * y;
            s1[i] = n1; s2[i] = n2; u = y;
        }
#pragma unroll
        for (int i = 0; i < NB; i++) {
            M1[(2 * i) * 32 + t]     = s1[i];
            M1[(2 * i + 1) * 32 + t] = s2[i];
        }
    }
    __syncthreads();

    // 14 squarings; save A^64 (sq=5), A^1024 (sq=9), A^16384 (sq=13).
    // thread t: column c=t&31, rows r0+{0,8,16,24}; conflict-free (m136).
    int c  = t & 31;
    int r0 = t >> 5;
    double* src = M1;
    double* dst = M2;
    for (int sq = 0; sq < 14; sq++) {
        double acc[4] = {0.0, 0.0, 0.0, 0.0};
        for (int k = 0; k < 32; k++) {
            double bv = src[k * 32 + c];
#pragma unroll
            for (int e = 0; e < 4; e++)
                acc[e] += src[(e * 8 + r0) * 32 + k] * bv;
        }
#pragma unroll
        for (int e = 0; e < 4; e++) dst[(e * 8 + r0) * 32 + c] = acc[e];
        __syncthreads();
        { double* tmp = src; src = dst; dst = tmp; }
        float* out_m = (sq == 5) ? A64 : (sq == 9) ? A1K : (sq == 13) ? A16K : nullptr;
        if (out_m) {
#pragma unroll
            for (int e = 0; e < 4; e++) {
                int idx = (e * 8 + r0) * 32 + c;
                out_m[b * 1024 + idx] = (float)src[idx];
            }
        }
        __syncthreads();
    }
}

// single half-split matvec step: q' = A q + add (add pre-masked to half 0)
__device__ __forceinline__ float mv_step(const float* ar, float q, float addv, int half) {
    float acc = addv;
#pragma unroll
    for (int t = 0; t < 16; t++)
        acc = fmaf(ar[t], __shfl(q, half * 16 + t, 64), acc);
    acc += __shfl_xor(acc, 32, 64);
    return acc;
}

// ---------------- K1: zero-init chunk states + sub-group totals -------------
__global__ __launch_bounds__(64, 1) void k1_pass1(const float* __restrict__ audio,
                                                  const float* __restrict__ coefs,
                                                  const float* __restrict__ A64,
                                                  float* __restrict__ P,
                                                  float* __restrict__ Qend) {
    int blk   = blockIdx.x;          // 0..1023
    int batch = blk >> 6;
    int grp   = blk & 63;
    int lane  = threadIdx.x;
    int chunk = grp * GRP + lane;

    const float* cf = coefs + batch * 96;
    float c0[NB], c1[NB], c2[NB], c3[NB], c4[NB];
#pragma unroll
    for (int i = 0; i < NB; i++) {
        c0[i] = cf[i * 5 + 0]; c1[i] = cf[i * 5 + 1]; c2[i] = cf[i * 5 + 2];
        c3[i] = cf[i * 5 + 3]; c4[i] = cf[i * 5 + 4];
    }
    float ing = cf[80];

    float s1[NB], s2[NB];
#pragma unroll
    for (int i = 0; i < NB; i++) { s1[i] = 0.f; s2[i] = 0.f; }

    const float4* xp = (const float4*)(audio + (size_t)batch * T_LEN + (size_t)chunk * L);
    float4 cur = xp[0];
    float4 nxt = xp[1];
#pragma unroll 1
    for (int tt = 0; tt < 16; tt++) {
        float4 fut = xp[(tt < 14) ? (tt + 2) : 15];
        float xs[4] = {cur.x, cur.y, cur.z, cur.w};
#pragma unroll
        for (int j = 0; j < 4; j++) {
            float u = ing * xs[j];
#pragma unroll
            for (int i = 0; i < NB; i++) {
                float y  = fmaf(c0[i], u, s1[i]);
                float n1 = fmaf(c1[i], u, s2[i]); n1 = fmaf(-c3[i], y, n1);
                float n2 = c2[i] * u;             n2 = fmaf(-c4[i], y, n2);
                s1[i] = n1; s2[i] = n2; u = y;
            }
        }
        cur = nxt; nxt = fut;
    }

    // P write: TRANSPOSED layout P[grp][state][chunk] -> 32 coalesced stores
    {
        float* pb = P + ((size_t)(batch * NG + grp)) * 2048;
#pragma unroll
        for (int i = 0; i < NB; i++) {
            pb[(2 * i) * 64 + lane]     = s1[i];
            pb[(2 * i + 1) * 64 + lane] = s2[i];
        }
    }

    // stage into LDS for the chains
    __shared__ float plds[GRP][33];
#pragma unroll
    for (int i = 0; i < NB; i++) {
        plds[lane][2 * i]     = s1[i];
        plds[lane][2 * i + 1] = s2[i];
    }
    __syncthreads();

    // 4 independent 16-step chains (half-split matvec)
    int row  = lane & 31;
    int half = lane >> 5;
    const float* alr = A64 + batch * 1024 + row * 32 + half * 16;
    float ar[16];
#pragma unroll
    for (int j = 0; j < 16; j++) ar[j] = alr[j];
    float q0 = 0.f, q1 = 0.f, q2 = 0.f, q3 = 0.f;
#pragma unroll 1
    for (int j = 0; j < SUB; j++) {
        float a0 = (half == 0) ? plds[0 * SUB + j][row] : 0.f;
        float a1 = (half == 0) ? plds[1 * SUB + j][row] : 0.f;
        float a2 = (half == 0) ? plds[2 * SUB + j][row] : 0.f;
        float a3 = (half == 0) ? plds[3 * SUB + j][row] : 0.f;
#pragma unroll
        for (int t = 0; t < 16; t++) {
            float w = ar[t];
            int src = half * 16 + t;
            a0 = fmaf(w, __shfl(q0, src, 64), a0);
            a1 = fmaf(w, __shfl(q1, src, 64), a1);
            a2 = fmaf(w, __shfl(q2, src, 64), a2);
            a3 = fmaf(w, __shfl(q3, src, 64), a3);
        }
        a0 += __shfl_xor(a0, 32, 64);
        a1 += __shfl_xor(a1, 32, 64);
        a2 += __shfl_xor(a2, 32, 64);
        a3 += __shfl_xor(a3, 32, 64);
        q0 = a0; q1 = a1; q2 = a2; q3 = a3;
    }
    if (lane < 32) {
        float* qe = Qend + ((size_t)(batch * NSUB + grp * CHAINS)) * 32 + row;
        qe[0] = q0; qe[32] = q1; qe[64] = q2; qe[96] = q3;
    }
}

// ---------------- K2: full hierarchical combine, one block per batch --------
// 4 waves: C1 = 16 sup-chains (4 per wave, 4-ILP); C2 = wave-0 super scan;
// C3 = seeded sub-scans -> Sarr. Replaces round-5's k2a/k2b/k2c (2 launches
// and their gaps eliminated).
__global__ __launch_bounds__(256, 1) void k2_combine(const float* __restrict__ A1K,
                                                     const float* __restrict__ A16K,
                                                     const float* __restrict__ Qend,
                                                     float* __restrict__ Sarr) {
    int batch = blockIdx.x;
    int tid   = threadIdx.x;
    int wave  = tid >> 6;
    int lane  = tid & 63;
    int row   = lane & 31;
    int half  = lane >> 5;

    __shared__ float qe[NSUB][32];   // 32 KB
    __shared__ float qs[NSUP][32];
    __shared__ float ss[NSUP][32];

    // cooperative coalesced stage of Qend[batch] (32 KB)
    {
        const float4* src4 = (const float4*)(Qend + (size_t)batch * NSUB * 32);
        float4* dst4 = (float4*)&qe[0][0];
        for (int i = tid; i < NSUB * 32 / 4; i += 256) dst4[i] = src4[i];
    }
    float ar1k[16];
    {
        const float* ap = A1K + batch * 1024 + row * 32 + half * 16;
#pragma unroll
        for (int j = 0; j < 16; j++) ar1k[j] = ap[j];
    }
    __syncthreads();

    // C1: wave w -> sups w*4..w*4+3 as 4-ILP chains
    int s0i = wave * 4;
    {
        float q0 = 0.f, q1 = 0.f, q2 = 0.f, q3 = 0.f;
#pragma unroll 1
        for (int j = 0; j < 16; j++) {
            float a0 = (half == 0) ? qe[(s0i + 0) * 16 + j][row] : 0.f;
            float a1 = (half == 0) ? qe[(s0i + 1) * 16 + j][row] : 0.f;
            float a2 = (half == 0) ? qe[(s0i + 2) * 16 + j][row] : 0.f;
            float a3 = (half == 0) ? qe[(s0i + 3) * 16 + j][row] : 0.f;
#pragma unroll
            for (int t = 0; t < 16; t++) {
                float w = ar1k[t];
                int src = half * 16 + t;
                a0 = fmaf(w, __shfl(q0, src, 64), a0);
                a1 = fmaf(w, __shfl(q1, src, 64), a1);
                a2 = fmaf(w, __shfl(q2, src, 64), a2);
                a3 = fmaf(w, __shfl(q3, src, 64), a3);
            }
            a0 += __shfl_xor(a0, 32, 64);
            a1 += __shfl_xor(a1, 32, 64);
            a2 += __shfl_xor(a2, 32, 64);
            a3 += __shfl_xor(a3, 32, 64);
            q0 = a0; q1 = a1; q2 = a2; q3 = a3;
        }
        if (lane < 32) {
            qs[s0i + 0][row] = q0; qs[s0i + 1][row] = q1;
            qs[s0i + 2][row] = q2; qs[s0i + 3][row] = q3;
        }
    }
    __syncthreads();

    // C2: wave 0 scans 16 supers with A^16384
    if (wave == 0) {
        float ark[16];
        const float* ap = A16K + batch * 1024 + row * 32 + half * 16;
#pragma unroll
        for (int j = 0; j < 16; j++) ark[j] = ap[j];
        float S = 0.f;
#pragma unroll 1
        for (int s = 0; s < 16; s++) {
            if (lane < 32) ss[s][row] = S;
            float addv = (half == 0) ? qs[s][row] : 0.f;
            S = mv_step(ark, S, addv, half);
        }
    }
    __syncthreads();

    // C3: seeded sub-scans -> Sarr (coalesced 128 B stores)
    {
        float q0 = ss[s0i + 0][row];   // replicated to both halves
        float q1 = ss[s0i + 1][row];
        float q2 = ss[s0i + 2][row];
        float q3 = ss[s0i + 3][row];
#pragma unroll 1
        for (int j = 0; j < 16; j++) {
            if (lane < 32) {
                Sarr[((size_t)(batch * NSUB + (s0i + 0) * 16 + j)) * 32 + row] = q0;
                Sarr[((size_t)(batch * NSUB + (s0i + 1) * 16 + j)) * 32 + row] = q1;
                Sarr[((size_t)(batch * NSUB + (s0i + 2) * 16 + j)) * 32 + row] = q2;
                Sarr[((size_t)(batch * NSUB + (s0i + 3) * 16 + j)) * 32 + row] = q3;
            }
            float a0 = (half == 0) ? qe[(s0i + 0) * 16 + j][row] : 0.f;
            float a1 = (half == 0) ? qe[(s0i + 1) * 16 + j][row] : 0.f;
            float a2 = (half == 0) ? qe[(s0i + 2) * 16 + j][row] : 0.f;
            float a3 = (half == 0) ? qe[(s0i + 3) * 16 + j][row] : 0.f;
#pragma unroll
            for (int t = 0; t < 16; t++) {
                float w = ar1k[t];
                int src = half * 16 + t;
                a0 = fmaf(w, __shfl(q0, src, 64), a0);
                a1 = fmaf(w, __shfl(q1, src, 64), a1);
                a2 = fmaf(w, __shfl(q2, src, 64), a2);
                a3 = fmaf(w, __shfl(q3, src, 64), a3);
            }
            a0 += __shfl_xor(a0, 32, 64);
            a1 += __shfl_xor(a1, 32, 64);
            a2 += __shfl_xor(a2, 32, 64);
            a3 += __shfl_xor(a3, 32, 64);
            q0 = a0; q1 = a1; q2 = a2; q3 = a3;
        }
    }
}

// ---------------- K3: corrected-init re-run, write output ----------------
__global__ __launch_bounds__(64, 1) void k3_pass2(const float* __restrict__ audio,
                                                  const float* __restrict__ coefs,
                                                  const float* __restrict__ A64,
                                                  const float* __restrict__ P,
                                                  const float* __restrict__ Sarr,
                                                  float* __restrict__ out) {
    int blk   = blockIdx.x;
    int batch = blk >> 6;
    int grp   = blk & 63;
    int lane  = threadIdx.x;
    int chunk = grp * GRP + lane;
    int row   = lane & 31;
    int half  = lane >> 5;

    __shared__ float plds[GRP][33];

    // coalesced P load (transposed layout) -> LDS transpose
    // ds_write addr (lane*33+s): banks (lane+s)%32 -> 2-way alias (free)
    {
        const float* pb = P + ((size_t)(batch * NG + grp)) * 2048;
        float pv[32];
#pragma unroll
        for (int s = 0; s < 32; s++) pv[s] = pb[s * 64 + lane];
#pragma unroll
        for (int s = 0; s < 32; s++) plds[lane][s] = pv[s];
    }
    __syncthreads();

    // 4 seeded chains; overwrite plds[k][row] in place with chunk-k start state
    {
        const float* alr = A64 + batch * 1024 + row * 32 + half * 16;
        float ar[16];
#pragma unroll
        for (int j = 0; j < 16; j++) ar[j] = alr[j];
        const float* sp = Sarr + ((size_t)(batch * NSUB + grp * CHAINS)) * 32 + row;
        float q0 = sp[0], q1 = sp[32], q2 = sp[64], q3 = sp[96];
#pragma unroll 1
        for (int j = 0; j < SUB; j++) {
            float a0 = (half == 0) ? plds[0 * SUB + j][row] : 0.f;
            float a1 = (half == 0) ? plds[1 * SUB + j][row] : 0.f;
            float a2 = (half == 0) ? plds[2 * SUB + j][row] : 0.f;
            float a3 = (half == 0) ? plds[3 * SUB + j][row] : 0.f;
            if (half == 0) {
                plds[0 * SUB + j][row] = q0;
                plds[1 * SUB + j][row] = q1;
                plds[2 * SUB + j][row] = q2;
                plds[3 * SUB + j][row] = q3;
            }
#pragma unroll
            for (int t = 0; t < 16; t++) {
                float w = ar[t];
                int src = half * 16 + t;
                a0 = fmaf(w, __shfl(q0, src, 64), a0);
                a1 = fmaf(w, __shfl(q1, src, 64), a1);
                a2 = fmaf(w, __shfl(q2, src, 64), a2);
                a3 = fmaf(w, __shfl(q3, src, 64), a3);
            }
            a0 += __shfl_xor(a0, 32, 64);
            a1 += __shfl_xor(a1, 32, 64);
            a2 += __shfl_xor(a2, 32, 64);
            a3 += __shfl_xor(a3, 32, 64);
            q0 = a0; q1 = a1; q2 = a2; q3 = a3;
        }
    }
    __syncthreads();

    const float* cf = coefs + batch * 96;
    float c0[NB], c1[NB], c2[NB], c3[NB], c4[NB];
#pragma unroll
    for (int i = 0; i < NB; i++) {
        c0[i] = cf[i * 5 + 0]; c1[i] = cf[i * 5 + 1]; c2[i] = cf[i * 5 + 2];
        c3[i] = cf[i * 5 + 3]; c4[i] = cf[i * 5 + 4];
    }
    float ing  = cf[80];
    float outg = cf[81];

    float s1[NB], s2[NB];
#pragma unroll
    for (int i = 0; i < NB; i++) {
        s1[i] = plds[lane][2 * i];
        s2[i] = plds[lane][2 * i + 1];
    }

    const float4* xp = (const float4*)(audio + (size_t)batch * T_LEN + (size_t)chunk * L);
    float4* yp = (float4*)(out + (size_t)batch * T_LEN + (size_t)chunk * L);
    float4 cur = xp[0];
    float4 nxt = xp[1];
#pragma unroll 1
    for (int tt = 0; tt < 16; tt++) {
        float4 fut = xp[(tt < 14) ? (tt + 2) : 15];
        float xs[4] = {cur.x, cur.y, cur.z, cur.w};
        float ys[4];
#pragma unroll
        for (int j = 0; j < 4; j++) {
            float u = ing * xs[j];
#pragma unroll
            for (int i = 0; i < NB; i++) {
                float y  = fmaf(c0[i], u, s1[i]);
                float n1 = fmaf(c1[i], u, s2[i]); n1 = fmaf(-c3[i], y, n1);
                float n2 = c2[i] * u;             n2 = fmaf(-c4[i], y, n2);
                s1[i] = n1; s2[i] = n2; u = y;
            }
            ys[j] = outg * u;
        }
        float4 yv; yv.x = ys[0]; yv.y = ys[1]; yv.z = ys[2]; yv.w = ys[3];
        yp[tt] = yv;
        cur = nxt; nxt = fut;
    }
}

// ---------------- launcher ----------------
extern "C" void kernel_launch(void* const* d_in, const int* in_sizes, int n_in,
                              void* d_out, int out_size, void* d_ws, size_t ws_size,
                              hipStream_t stream) {
    const float* audio  = (const float*)d_in[0];
    const float* params = (const float*)d_in[1];
    float* out = (float*)d_out;
    float* ws  = (float*)d_ws;

    float* coefs = ws + OFF_COEF;
    float* A64   = ws + OFF_A64;
    float* A1K   = ws + OFF_A1K;
    float* A16K  = ws + OFF_A16K;
    float* Qend  = ws + OFF_QEND;
    float* Sarr  = ws + OFF_SARR;
    float* P     = ws + OFF_P;

    k0_setup<<<BATCH, 256, 0, stream>>>(params, coefs, A64, A1K, A16K);
    k1_pass1<<<BATCH * NG, 64, 0, stream>>>(audio, coefs, A64, P, Qend);
    k2_combine<<<BATCH, 256, 0, stream>>>(A1K, A16K, Qend, Sarr);
    k3_pass2<<<BATCH * NG, 64, 0, stream>>>(audio, coefs, A64, P, Sarr, out);
}